// Round 1
// 419.130 us; speedup vs baseline: 1.0326x; 1.0326x over previous
//
#include <hip/hip_runtime.h>
#include <math.h>

// Problem constants
#define BN   128    // batch
#define LN   2048   // encoder length
#define HN   256    // hidden
#define EN   256    // embed
#define CHUNKS 8
#define ROWS_PER_CHUNK (LN / CHUNKS)   // 256 rows per chunk, 64 per wave
#define PSTRIDE 260                    // per-(b,chunk) partial: ctx[256], m, s, pad

__device__ __forceinline__ float sigmoidf_(float x) { return 1.0f / (1.0f + __expf(-x)); }
__device__ __forceinline__ float tanhf_(float x)    { return 1.0f - 2.0f / (__expf(2.0f * x) + 1.0f); }

// ---------------------------------------------------------------------------
// K1: one pass over encoder_outputs with online softmax.
// grid (CHUNKS, BN), block 256 (4 waves). Wave w handles 64 consecutive rows.
// Partial per (b,chunk): unnormalized ctx at scale M, plus M and S.
// ---------------------------------------------------------------------------
__global__ __launch_bounds__(256) void attn_partial(
    const float* __restrict__ enc,      // [B][L][H]
    const float* __restrict__ hidden1,  // [B][H]
    float* __restrict__ partials)       // [B][CHUNKS][PSTRIDE]
{
    const int chunk = blockIdx.x;
    const int b     = blockIdx.y;
    const int t     = threadIdx.x;
    const int wave  = t >> 6;
    const int lane  = t & 63;

    __shared__ float lds_ctx[4][256];
    __shared__ float lds_m[4], lds_s[4];

    const float4 h4 = *(const float4*)(hidden1 + b * HN + lane * 4);

    float  m = -INFINITY, s = 0.0f;
    float4 ctx = make_float4(0.f, 0.f, 0.f, 0.f);

    const float* rowp = enc + ((size_t)b * LN + (size_t)chunk * ROWS_PER_CHUNK + wave * 64) * HN + lane * 4;

    #pragma unroll 2
    for (int r = 0; r < 64; ++r) {
        float4 e = *(const float4*)rowp;
        rowp += HN;
        float d = e.x * h4.x + e.y * h4.y + e.z * h4.z + e.w * h4.w;
        #pragma unroll
        for (int off = 32; off > 0; off >>= 1) d += __shfl_xor(d, off, 64);
        // online softmax update
        float mn   = fmaxf(m, d);
        float corr = __expf(m - mn);   // exp(-inf)=0 on first iter
        float p    = __expf(d - mn);
        s = s * corr + p;
        ctx.x = ctx.x * corr + p * e.x;
        ctx.y = ctx.y * corr + p * e.y;
        ctx.z = ctx.z * corr + p * e.z;
        ctx.w = ctx.w * corr + p * e.w;
        m = mn;
    }

    *(float4*)&lds_ctx[wave][lane * 4] = ctx;
    if (lane == 0) { lds_m[wave] = m; lds_s[wave] = s; }
    __syncthreads();

    // combine the 4 waves; thread t == h-index j
    float M = fmaxf(fmaxf(lds_m[0], lds_m[1]), fmaxf(lds_m[2], lds_m[3]));
    float e0 = __expf(lds_m[0] - M), e1 = __expf(lds_m[1] - M);
    float e2 = __expf(lds_m[2] - M), e3 = __expf(lds_m[3] - M);
    float cj = e0 * lds_ctx[0][t] + e1 * lds_ctx[1][t] + e2 * lds_ctx[2][t] + e3 * lds_ctx[3][t];
    float S  = e0 * lds_s[0] + e1 * lds_s[1] + e2 * lds_s[2] + e3 * lds_s[3];

    float* pb = partials + ((size_t)b * CHUNKS + chunk) * PSTRIDE;
    pb[t] = cj;
    if (t == 0) { pb[256] = M; pb[257] = S; }
}

// ---------------------------------------------------------------------------
// K2: fused chunk-combine + LSTM1.
// grid (32 j-blocks, 8 b-blocks), block 128 = 16 b x 8 j.
// Phase A: per-block softmax-combine of the 8 chunk partials for its 16 b's,
//          building xs[b_local][512] = [ctx | h1_prev] in XOR-swizzled LDS.
// Phase B: gates in two K=256 halves (half0 = w_ih over ctx, half1 = w_hh over
//          h1_prev). Weight staging uses interleaved-row mapping (row = idx&31,
//          kf = idx>>5) + group XOR swizzle (jl ^ (kf&7)) so the transpose
//          writes are ~2-way (vs 64-way before) and ds_read_b128 stays
//          conflict-free (per-k the 8 swizzled groups tile all 32 banks).
// LDS = 32 KiB wq + 32 KiB xs = 64 KiB exactly.
// ---------------------------------------------------------------------------
#define STAGE_W1(Wp)                                                          \
    {                                                                         \
        _Pragma("unroll")                                                     \
        for (int it = 0; it < 16; ++it) {                                     \
            const int idx = it * 128 + t;                                     \
            const int row = idx & 31;        /* = t&31 */                     \
            const int kf  = idx >> 5;        /* it*4 + (t>>5), 0..63 */       \
            const int q   = row >> 3, jl0 = row & 7;                          \
            const int g   = q * 256 + jb * 8 + jl0;                           \
            float4 v = *(const float4*)((Wp) + (size_t)g * 256 + kf * 4);     \
            const int pos = ((jl0 ^ (kf & 7)) << 2) + q;                      \
            wq[kf * 128 +  0 + pos] = v.x;                                    \
            wq[kf * 128 + 32 + pos] = v.y;                                    \
            wq[kf * 128 + 64 + pos] = v.z;                                    \
            wq[kf * 128 + 96 + pos] = v.w;                                    \
        }                                                                     \
    }

__global__ __launch_bounds__(128) void lstm1_fused(
    const float* __restrict__ partials, // [B][CHUNKS][PSTRIDE]
    const float* __restrict__ hidden1,  // [B][256]
    const float* __restrict__ w_ih,     // [1024][256]
    const float* __restrict__ w_hh,     // [1024][256]
    const float* __restrict__ b_ih,
    const float* __restrict__ b_hh,
    const float* __restrict__ cell,     // [B][256]
    float* __restrict__ h_out,
    float* __restrict__ c_out)
{
    __shared__ float wq[256 * 32];      // one K-half, [k][group(8)][q(4)], 32 KiB
    __shared__ float xs[16 * 512];      // [b_local][128 float4-groups], swizzled, 32 KiB
    const int t  = threadIdx.x;
    const int jb = blockIdx.x;          // 0..31
    const int bb = blockIdx.y;          // 0..7

    // stage half 0 (w_ih1) first so its global loads fly under phase A
    STAGE_W1(w_ih);

    // ---- phase A: combine chunk partials -> xs = [ctx | h1_prev] ----
    {
        const int g  = t >> 3;          // b-local 0..15
        const int l8 = t & 7;
        const int b  = bb * 16 + g;
        const float* pb = partials + (size_t)b * CHUNKS * PSTRIDE;

        float mk[CHUNKS], ek[CHUNKS];
        float M = -INFINITY;
        #pragma unroll
        for (int k = 0; k < CHUNKS; ++k) { mk[k] = pb[k * PSTRIDE + 256]; M = fmaxf(M, mk[k]); }
        float S = 0.0f;
        #pragma unroll
        for (int k = 0; k < CHUNKS; ++k) { ek[k] = __expf(mk[k] - M); S += ek[k] * pb[k * PSTRIDE + 257]; }
        const float invS = 1.0f / S;

        #pragma unroll
        for (int it = 0; it < 8; ++it) {
            const int j4 = it * 8 + l8;                // ctx float4-group 0..63
            float cx = 0.f, cy = 0.f, cz = 0.f, cw = 0.f;
            #pragma unroll
            for (int k = 0; k < CHUNKS; ++k) {
                float4 p4 = *(const float4*)(pb + k * PSTRIDE + j4 * 4);
                cx += ek[k] * p4.x; cy += ek[k] * p4.y;
                cz += ek[k] * p4.z; cw += ek[k] * p4.w;
            }
            *(float4*)&xs[g * 512 + ((j4 ^ (g & 7)) << 2)] =
                make_float4(cx * invS, cy * invS, cz * invS, cw * invS);
        }
        const float* hr = hidden1 + (size_t)b * HN;
        #pragma unroll
        for (int it = 0; it < 8; ++it) {
            const int j4 = it * 8 + l8;                // h groups 64..127
            float4 hv = *(const float4*)(hr + j4 * 4);
            *(float4*)&xs[g * 512 + (((64 + j4) ^ (g & 7)) << 2)] = hv;
        }
    }
    __syncthreads();

    const int jl = t & 7, bl = t >> 3;
    const int b = bb * 16 + bl;
    const int j = jb * 8 + jl;

    float acc0 = 0.f, acc1 = 0.f, acc2 = 0.f, acc3 = 0.f;

    // ---- dot half 0: ctx x w_ih ----
    #pragma unroll 4
    for (int k4 = 0; k4 < 64; ++k4) {
        float4 xv = *(const float4*)&xs[bl * 512 + ((k4 ^ (bl & 7)) << 2)];
        const int pos = (jl ^ (k4 & 7)) << 2;
        #pragma unroll
        for (int i = 0; i < 4; ++i) {
            float xe = (i == 0) ? xv.x : (i == 1) ? xv.y : (i == 2) ? xv.z : xv.w;
            float4 w4 = *(const float4*)&wq[(k4 * 4 + i) * 32 + pos];
            acc0 += w4.x * xe; acc1 += w4.y * xe; acc2 += w4.z * xe; acc3 += w4.w * xe;
        }
    }
    __syncthreads();          // wq WAR before restage

    STAGE_W1(w_hh);
    __syncthreads();

    // ---- dot half 1: h1_prev x w_hh ----
    #pragma unroll 4
    for (int k4 = 0; k4 < 64; ++k4) {
        float4 xv = *(const float4*)&xs[bl * 512 + (((64 + k4) ^ (bl & 7)) << 2)];
        const int pos = (jl ^ (k4 & 7)) << 2;
        #pragma unroll
        for (int i = 0; i < 4; ++i) {
            float xe = (i == 0) ? xv.x : (i == 1) ? xv.y : (i == 2) ? xv.z : xv.w;
            float4 w4 = *(const float4*)&wq[(k4 * 4 + i) * 32 + pos];
            acc0 += w4.x * xe; acc1 += w4.y * xe; acc2 += w4.z * xe; acc3 += w4.w * xe;
        }
    }

    float gi = acc0 + b_ih[j]       + b_hh[j];
    float gf = acc1 + b_ih[256 + j] + b_hh[256 + j];
    float gg = acc2 + b_ih[512 + j] + b_hh[512 + j];
    float go = acc3 + b_ih[768 + j] + b_hh[768 + j];

    float cp = cell[b * HN + j];
    float cn = sigmoidf_(gf) * cp + sigmoidf_(gi) * tanhf_(gg);
    float hn = sigmoidf_(go) * tanhf_(cn);

    c_out[b * HN + j] = cn;
    h_out[b * HN + j] = hn;
}

// ---------------------------------------------------------------------------
// K3: LSTM2. K=768 read directly from [embed | h1 | h2_prev] (xh2 buffer
// eliminated). grid (64 j-blocks, 4 b-blocks), block 128 = 32 b x 4 j.
// Weight staging: interleaved-row mapping (row = idx&15, kf = idx>>4) +
// group XOR (jl ^ (kf&3)) -> ~4-way writes (vs 64-way before); reads stay
// conflict-free b128. wq = 48 KiB.
// ---------------------------------------------------------------------------
__global__ __launch_bounds__(128) void lstm2_kernel(
    const float* __restrict__ embed,    // [B][256]
    const float* __restrict__ h1,       // [B][256] (lstm1 output)
    const float* __restrict__ hidden2,  // [B][256]
    const float* __restrict__ w_ih,     // [1024][512]
    const float* __restrict__ w_hh,     // [1024][256]
    const float* __restrict__ b_ih,
    const float* __restrict__ b_hh,
    const float* __restrict__ cell,     // [B][256]
    float* __restrict__ out0,           // d_out chunk 0 (outputs == h2)
    float* __restrict__ h_out,          // d_out chunk 3
    float* __restrict__ c_out)          // d_out chunk 4
{
    __shared__ float wq[768 * 16];      // [k][group(4)][q(4)], 48 KiB
    const int t  = threadIdx.x;
    const int jb = blockIdx.x;          // 0..63
    const int bb = blockIdx.y;          // 0..3

    #pragma unroll
    for (int it = 0; it < 24; ++it) {
        const int idx = it * 128 + t;
        const int row = idx & 15;            // = t&15
        const int kf  = idx >> 4;            // it*8 + (t>>4), 0..191
        const int q   = row >> 2, jl0 = row & 3;
        const int g   = q * 256 + jb * 4 + jl0;
        const int k0  = kf * 4;
        const float* src = (k0 < 512) ? (w_ih + (size_t)g * 512 + k0)
                                      : (w_hh + (size_t)g * 256 + (k0 - 512));
        float4 v = *(const float4*)src;
        const int pos = ((jl0 ^ (kf & 3)) << 2) + q;
        wq[kf * 64 +  0 + pos] = v.x;
        wq[kf * 64 + 16 + pos] = v.y;
        wq[kf * 64 + 32 + pos] = v.z;
        wq[kf * 64 + 48 + pos] = v.w;
    }
    __syncthreads();

    const int jl = t & 3, bl = t >> 2;
    const int b = bb * 32 + bl;
    const int j = jb * 4 + jl;

    float acc0 = 0.f, acc1 = 0.f, acc2 = 0.f, acc3 = 0.f;
    const float* xsrc[3] = { embed   + (size_t)b * EN,
                             h1      + (size_t)b * HN,
                             hidden2 + (size_t)b * HN };
    #pragma unroll
    for (int seg = 0; seg < 3; ++seg) {
        const float* xr = xsrc[seg];
        #pragma unroll 4
        for (int k4 = 0; k4 < 64; ++k4) {
            const int kf = seg * 64 + k4;
            float4 xv = *(const float4*)(xr + k4 * 4);
            const int pos = (jl ^ (k4 & 3)) << 2;   // kf&3 == k4&3
            #pragma unroll
            for (int i = 0; i < 4; ++i) {
                float xe = (i == 0) ? xv.x : (i == 1) ? xv.y : (i == 2) ? xv.z : xv.w;
                float4 w4 = *(const float4*)&wq[(kf * 4 + i) * 16 + pos];
                acc0 += w4.x * xe; acc1 += w4.y * xe; acc2 += w4.z * xe; acc3 += w4.w * xe;
            }
        }
    }

    float gi = acc0 + b_ih[j]       + b_hh[j];
    float gf = acc1 + b_ih[256 + j] + b_hh[256 + j];
    float gg = acc2 + b_ih[512 + j] + b_hh[512 + j];
    float go = acc3 + b_ih[768 + j] + b_hh[768 + j];

    float cp = cell[b * HN + j];
    float cn = sigmoidf_(gf) * cp + sigmoidf_(gi) * tanhf_(gg);
    float hn = sigmoidf_(go) * tanhf_(cn);

    out0[b * HN + j]  = hn;   // outputs chunk (== h2)
    h_out[b * HN + j] = hn;   // h2 chunk
    c_out[b * HN + j] = cn;   // c2 chunk
}

// ---------------------------------------------------------------------------
extern "C" void kernel_launch(void* const* d_in, const int* in_sizes, int n_in,
                              void* d_out, int out_size, void* d_ws, size_t ws_size,
                              hipStream_t stream)
{
    const float* embed   = (const float*)d_in[0];   // (B,1,E)
    const float* enc     = (const float*)d_in[1];   // (B,L,H)
    const float* hidden1 = (const float*)d_in[2];   // (1,B,H)
    const float* cell1   = (const float*)d_in[3];
    const float* hidden2 = (const float*)d_in[4];
    const float* cell2   = (const float*)d_in[5];
    const float* w_ih1   = (const float*)d_in[6];   // (1024,256)
    const float* w_hh1   = (const float*)d_in[7];   // (1024,256)
    const float* b_ih1   = (const float*)d_in[8];
    const float* b_hh1   = (const float*)d_in[9];
    const float* w_ih2   = (const float*)d_in[10];  // (1024,512)
    const float* w_hh2   = (const float*)d_in[11];  // (1024,256)
    const float* b_ih2   = (const float*)d_in[12];
    const float* b_hh2   = (const float*)d_in[13];

    float* out = (float*)d_out;
    // out layout: [0) outputs(h2) 32768 | 32768) h1 | 65536) c1 | 98304) h2 | 131072) c2
    float* ws = (float*)d_ws;
    float* partials = ws;                                  // 128*8*260 floats

    attn_partial<<<dim3(CHUNKS, BN), 256, 0, stream>>>(enc, hidden1, partials);
    lstm1_fused<<<dim3(32, 8), 128, 0, stream>>>(partials, hidden1, w_ih1, w_hh1,
                                                 b_ih1, b_hh1, cell1,
                                                 out + 32768, out + 65536);
    lstm2_kernel<<<dim3(64, 4), 128, 0, stream>>>(embed, out + 32768, hidden2,
                                                  w_ih2, w_hh2, b_ih2, b_hh2, cell2,
                                                  out, out + 98304, out + 131072);
}

// Round 2
// 410.311 us; speedup vs baseline: 1.0548x; 1.0215x over previous
//
#include <hip/hip_runtime.h>
#include <math.h>

// Problem constants
#define BN   128    // batch
#define LN   2048   // encoder length
#define HN   256    // hidden
#define EN   256    // embed
#define CHUNKS 8
#define ROWS_PER_CHUNK (LN / CHUNKS)   // 256 rows per chunk, 64 per wave
#define PSTRIDE 260                    // per-(b,chunk) partial: ctx[256], m, s, pad

__device__ __forceinline__ float sigmoidf_(float x) { return 1.0f / (1.0f + __expf(-x)); }
__device__ __forceinline__ float tanhf_(float x)    { return 1.0f - 2.0f / (__expf(2.0f * x) + 1.0f); }

// ---------------------------------------------------------------------------
// K1: one pass over encoder_outputs with online softmax.
// grid (CHUNKS, BN), block 256 (4 waves). Wave w handles 64 consecutive rows.
// Partial per (b,chunk): unnormalized ctx at scale M, plus M and S.
// ---------------------------------------------------------------------------
__global__ __launch_bounds__(256) void attn_partial(
    const float* __restrict__ enc,      // [B][L][H]
    const float* __restrict__ hidden1,  // [B][H]
    float* __restrict__ partials)       // [B][CHUNKS][PSTRIDE]
{
    const int chunk = blockIdx.x;
    const int b     = blockIdx.y;
    const int t     = threadIdx.x;
    const int wave  = t >> 6;
    const int lane  = t & 63;

    __shared__ float lds_ctx[4][256];
    __shared__ float lds_m[4], lds_s[4];

    const float4 h4 = *(const float4*)(hidden1 + b * HN + lane * 4);

    float  m = -INFINITY, s = 0.0f;
    float4 ctx = make_float4(0.f, 0.f, 0.f, 0.f);

    const float* rowp = enc + ((size_t)b * LN + (size_t)chunk * ROWS_PER_CHUNK + wave * 64) * HN + lane * 4;

    #pragma unroll 4
    for (int r = 0; r < 64; ++r) {
        float4 e = *(const float4*)rowp;
        rowp += HN;
        float d = e.x * h4.x + e.y * h4.y + e.z * h4.z + e.w * h4.w;
        #pragma unroll
        for (int off = 32; off > 0; off >>= 1) d += __shfl_xor(d, off, 64);
        // online softmax update
        float mn   = fmaxf(m, d);
        float corr = __expf(m - mn);   // exp(-inf)=0 on first iter
        float p    = __expf(d - mn);
        s = s * corr + p;
        ctx.x = ctx.x * corr + p * e.x;
        ctx.y = ctx.y * corr + p * e.y;
        ctx.z = ctx.z * corr + p * e.z;
        ctx.w = ctx.w * corr + p * e.w;
        m = mn;
    }

    *(float4*)&lds_ctx[wave][lane * 4] = ctx;
    if (lane == 0) { lds_m[wave] = m; lds_s[wave] = s; }
    __syncthreads();

    // combine the 4 waves; thread t == h-index j
    float M = fmaxf(fmaxf(lds_m[0], lds_m[1]), fmaxf(lds_m[2], lds_m[3]));
    float e0 = __expf(lds_m[0] - M), e1 = __expf(lds_m[1] - M);
    float e2 = __expf(lds_m[2] - M), e3 = __expf(lds_m[3] - M);
    float cj = e0 * lds_ctx[0][t] + e1 * lds_ctx[1][t] + e2 * lds_ctx[2][t] + e3 * lds_ctx[3][t];
    float S  = e0 * lds_s[0] + e1 * lds_s[1] + e2 * lds_s[2] + e3 * lds_s[3];

    float* pb = partials + ((size_t)b * CHUNKS + chunk) * PSTRIDE;
    pb[t] = cj;
    if (t == 0) { pb[256] = M; pb[257] = S; }
}

// ---------------------------------------------------------------------------
// K2: fused chunk-combine + LSTM1, single-stage K-split version.
// grid (32 j-blocks, 8 b-blocks), block 256 = 4 waves (all 4 SIMDs busy).
// Threads t<128 compute the ctx x w_ih K-half, t>=128 the h1_prev x w_hh
// K-half (wave-uniform split); partial gate sums combined via a 2 KiB LDS
// reduce. Both weight halves staged ONCE up front (no mid-kernel restage):
//   wq [2 halves][256 k][8 jl][4 q] = 64 KiB
//   xs [16 b][128 float4-groups]    = 32 KiB (XOR-swizzled by (b&7))
//   red[128][4]                     =  2 KiB
// Staging uses row-in-lane mapping: per wave-instr lanes span (half,row) so
// transpose writes are exactly 2-way (free). All dot reads conflict-free
// (8 broadcast groups x 4 banks tile all 32 banks).
// ---------------------------------------------------------------------------
__global__ __launch_bounds__(256) void lstm1_fused(
    const float* __restrict__ partials, // [B][CHUNKS][PSTRIDE]
    const float* __restrict__ hidden1,  // [B][256]
    const float* __restrict__ w_ih,     // [1024][256]
    const float* __restrict__ w_hh,     // [1024][256]
    const float* __restrict__ b_ih,
    const float* __restrict__ b_hh,
    const float* __restrict__ cell,     // [B][256]
    float* __restrict__ h_out,
    float* __restrict__ c_out)
{
    __shared__ float wq[2 * 256 * 32];  // 64 KiB
    __shared__ float xs[16 * 512];      // 32 KiB
    __shared__ float red[128 * 4];      //  2 KiB
    const int t  = threadIdx.x;
    const int jb = blockIdx.x;          // 0..31
    const int bb = blockIdx.y;          // 0..7

    // ---- stage both K-halves: 4096 float4s, row-in-lane mapping ----
    {
        const int ri   = t & 63;        // row-instance: constant per thread
        const int half = ri >> 5;
        const int row  = ri & 31;
        const int q = row >> 3, jl0 = row & 7;
        const int g = q * 256 + jb * 8 + jl0;
        const float* W = half ? w_hh : w_ih;
        #pragma unroll
        for (int it = 0; it < 16; ++it) {
            const int kf = it * 4 + (t >> 6);       // 0..63
            float4 v = *(const float4*)(W + (size_t)g * 256 + kf * 4);
            const int base = half * 8192 + kf * 128 + ((jl0 ^ (kf & 7)) << 2) + q;
            wq[base +  0] = v.x;
            wq[base + 32] = v.y;
            wq[base + 64] = v.z;
            wq[base + 96] = v.w;
        }
    }

    // ---- phase A: combine chunk partials -> xs = [ctx | h1_prev] ----
    {
        const int g   = t >> 4;         // b-local 0..15
        const int l16 = t & 15;
        const int b   = bb * 16 + g;
        const float* pb = partials + (size_t)b * CHUNKS * PSTRIDE;

        float mk[CHUNKS], ek[CHUNKS];
        float M = -INFINITY;
        #pragma unroll
        for (int k = 0; k < CHUNKS; ++k) { mk[k] = pb[k * PSTRIDE + 256]; M = fmaxf(M, mk[k]); }
        float S = 0.0f;
        #pragma unroll
        for (int k = 0; k < CHUNKS; ++k) { ek[k] = __expf(mk[k] - M); S += ek[k] * pb[k * PSTRIDE + 257]; }
        const float invS = 1.0f / S;

        #pragma unroll
        for (int it = 0; it < 4; ++it) {
            const int j4 = it * 16 + l16;           // ctx float4-group 0..63
            float cx = 0.f, cy = 0.f, cz = 0.f, cw = 0.f;
            #pragma unroll
            for (int k = 0; k < CHUNKS; ++k) {
                float4 p4 = *(const float4*)(pb + k * PSTRIDE + j4 * 4);
                cx += ek[k] * p4.x; cy += ek[k] * p4.y;
                cz += ek[k] * p4.z; cw += ek[k] * p4.w;
            }
            *(float4*)&xs[g * 512 + ((j4 ^ (g & 7)) << 2)] =
                make_float4(cx * invS, cy * invS, cz * invS, cw * invS);
        }
        const float* hr = hidden1 + (size_t)b * HN;
        #pragma unroll
        for (int it = 0; it < 4; ++it) {
            const int j4 = it * 16 + l16;           // h groups 64..127
            float4 hv = *(const float4*)(hr + j4 * 4);
            *(float4*)&xs[g * 512 + (((64 + j4) ^ (g & 7)) << 2)] = hv;
        }
    }
    __syncthreads();

    // ---- dot: each thread does its K-half (256) for one (b, j) ----
    const int jl = t & 7;
    const int bl = (t >> 3) & 15;
    const int kh = t >> 7;              // wave-uniform (waves 0,1 vs 2,3)
    const int b = bb * 16 + bl;
    const int j = jb * 8 + jl;

    float acc0 = 0.f, acc1 = 0.f, acc2 = 0.f, acc3 = 0.f;
    const int xbase = bl * 512;
    const int wbase = kh * 8192;
    #pragma unroll 4
    for (int k4 = 0; k4 < 64; ++k4) {
        float4 xv = *(const float4*)&xs[xbase + (((kh << 6) + (k4 ^ (bl & 7))) << 2)];
        const int pos = (jl ^ (k4 & 7)) << 2;
        #pragma unroll
        for (int i = 0; i < 4; ++i) {
            float xe = (i == 0) ? xv.x : (i == 1) ? xv.y : (i == 2) ? xv.z : xv.w;
            float4 w4 = *(const float4*)&wq[wbase + (k4 * 4 + i) * 32 + pos];
            acc0 += w4.x * xe; acc1 += w4.y * xe; acc2 += w4.z * xe; acc3 += w4.w * xe;
        }
    }

    if (kh == 1) *(float4*)&red[(t - 128) * 4] = make_float4(acc0, acc1, acc2, acc3);
    __syncthreads();

    if (kh == 0) {
        float4 r = *(const float4*)&red[t * 4];
        acc0 += r.x; acc1 += r.y; acc2 += r.z; acc3 += r.w;

        float gi = acc0 + b_ih[j]       + b_hh[j];
        float gf = acc1 + b_ih[256 + j] + b_hh[256 + j];
        float gg = acc2 + b_ih[512 + j] + b_hh[512 + j];
        float go = acc3 + b_ih[768 + j] + b_hh[768 + j];

        float cp = cell[b * HN + j];
        float cn = sigmoidf_(gf) * cp + sigmoidf_(gi) * tanhf_(gg);
        float hn = sigmoidf_(go) * tanhf_(cn);

        c_out[b * HN + j] = cn;
        h_out[b * HN + j] = hn;
    }
}

// ---------------------------------------------------------------------------
// K3: LSTM2, K-split version. K=768 = [embed(256) | h1(256) | h2_prev(256)],
// read directly from global. Threads t<128 do k 0..383 (embed + h1-lo),
// t>=128 do k 384..767 (h1-hi + h2), LDS pairwise reduce.
// grid (64 j-blocks, 4 b-blocks), block 256 = 32 b x 4 j x 2 k-halves.
// wq [192 kf][4 d][4 jl][4 q] = 48 KiB + red 2 KiB.
// ---------------------------------------------------------------------------
#define DOT2(KF, PTR)                                                         \
    {                                                                         \
        float4 xv = *(const float4*)(PTR);                                    \
        const int pos = (jl ^ ((KF) & 3)) << 2;                               \
        const float* wp = &wq[(KF) * 64 + pos];                               \
        float4 w0 = *(const float4*)(wp);                                     \
        float4 w1 = *(const float4*)(wp + 16);                                \
        float4 w2 = *(const float4*)(wp + 32);                                \
        float4 w3 = *(const float4*)(wp + 48);                                \
        acc0 += w0.x * xv.x + w1.x * xv.y + w2.x * xv.z + w3.x * xv.w;        \
        acc1 += w0.y * xv.x + w1.y * xv.y + w2.y * xv.z + w3.y * xv.w;        \
        acc2 += w0.z * xv.x + w1.z * xv.y + w2.z * xv.z + w3.z * xv.w;        \
        acc3 += w0.w * xv.x + w1.w * xv.y + w2.w * xv.z + w3.w * xv.w;        \
    }

__global__ __launch_bounds__(256) void lstm2_kernel(
    const float* __restrict__ embed,    // [B][256]
    const float* __restrict__ h1,       // [B][256] (lstm1 output)
    const float* __restrict__ hidden2,  // [B][256]
    const float* __restrict__ w_ih,     // [1024][512]
    const float* __restrict__ w_hh,     // [1024][256]
    const float* __restrict__ b_ih,
    const float* __restrict__ b_hh,
    const float* __restrict__ cell,     // [B][256]
    float* __restrict__ out0,           // d_out chunk 0 (outputs == h2)
    float* __restrict__ h_out,          // d_out chunk 3
    float* __restrict__ c_out)          // d_out chunk 4
{
    __shared__ float wq[768 * 16];      // 48 KiB
    __shared__ float red[128 * 4];      //  2 KiB
    const int t  = threadIdx.x;
    const int jb = blockIdx.x;          // 0..63
    const int bb = blockIdx.y;          // 0..3

    // stage 16 gate rows x 768 k = 3072 float4s; row-in-lane mapping
    #pragma unroll
    for (int it = 0; it < 12; ++it) {
        const int idx = it * 256 + t;
        const int row = idx & 15;            // = t&15
        const int kf  = idx >> 4;            // it*16 + (t>>4), 0..191
        const int q   = row >> 2, jl0 = row & 3;
        const int g   = q * 256 + jb * 4 + jl0;
        const int k0  = kf * 4;
        const float* src = (k0 < 512) ? (w_ih + (size_t)g * 512 + k0)
                                      : (w_hh + (size_t)g * 256 + (k0 - 512));
        float4 v = *(const float4*)src;
        const int pos = ((jl0 ^ (kf & 3)) << 2) + q;
        wq[kf * 64 +  0 + pos] = v.x;
        wq[kf * 64 + 16 + pos] = v.y;
        wq[kf * 64 + 32 + pos] = v.z;
        wq[kf * 64 + 48 + pos] = v.w;
    }
    __syncthreads();

    const int jl = t & 3;
    const int bl = (t >> 2) & 31;
    const int kh = t >> 7;              // wave-uniform
    const int b = bb * 32 + bl;
    const int j = jb * 4 + jl;

    float acc0 = 0.f, acc1 = 0.f, acc2 = 0.f, acc3 = 0.f;

    if (kh == 0) {
        const float* xe_ = embed + (size_t)b * EN;
        #pragma unroll 4
        for (int k4 = 0; k4 < 64; ++k4)  DOT2(k4, xe_ + k4 * 4);
        const float* xh_ = h1 + (size_t)b * HN;
        #pragma unroll 4
        for (int k4 = 64; k4 < 96; ++k4) DOT2(k4, xh_ + (k4 - 64) * 4);
    } else {
        const float* xh_ = h1 + (size_t)b * HN;
        #pragma unroll 4
        for (int k4 = 96; k4 < 128; ++k4)  DOT2(k4, xh_ + (k4 - 64) * 4);
        const float* xc_ = hidden2 + (size_t)b * HN;
        #pragma unroll 4
        for (int k4 = 128; k4 < 192; ++k4) DOT2(k4, xc_ + (k4 - 128) * 4);
    }

    if (kh == 1) *(float4*)&red[(t - 128) * 4] = make_float4(acc0, acc1, acc2, acc3);
    __syncthreads();

    if (kh == 0) {
        float4 r = *(const float4*)&red[t * 4];
        acc0 += r.x; acc1 += r.y; acc2 += r.z; acc3 += r.w;

        float gi = acc0 + b_ih[j]       + b_hh[j];
        float gf = acc1 + b_ih[256 + j] + b_hh[256 + j];
        float gg = acc2 + b_ih[512 + j] + b_hh[512 + j];
        float go = acc3 + b_ih[768 + j] + b_hh[768 + j];

        float cp = cell[b * HN + j];
        float cn = sigmoidf_(gf) * cp + sigmoidf_(gi) * tanhf_(gg);
        float hn = sigmoidf_(go) * tanhf_(cn);

        out0[b * HN + j]  = hn;   // outputs chunk (== h2)
        h_out[b * HN + j] = hn;   // h2 chunk
        c_out[b * HN + j] = cn;   // c2 chunk
    }
}

// ---------------------------------------------------------------------------
extern "C" void kernel_launch(void* const* d_in, const int* in_sizes, int n_in,
                              void* d_out, int out_size, void* d_ws, size_t ws_size,
                              hipStream_t stream)
{
    const float* embed   = (const float*)d_in[0];   // (B,1,E)
    const float* enc     = (const float*)d_in[1];   // (B,L,H)
    const float* hidden1 = (const float*)d_in[2];   // (1,B,H)
    const float* cell1   = (const float*)d_in[3];
    const float* hidden2 = (const float*)d_in[4];
    const float* cell2   = (const float*)d_in[5];
    const float* w_ih1   = (const float*)d_in[6];   // (1024,256)
    const float* w_hh1   = (const float*)d_in[7];   // (1024,256)
    const float* b_ih1   = (const float*)d_in[8];
    const float* b_hh1   = (const float*)d_in[9];
    const float* w_ih2   = (const float*)d_in[10];  // (1024,512)
    const float* w_hh2   = (const float*)d_in[11];  // (1024,256)
    const float* b_ih2   = (const float*)d_in[12];
    const float* b_hh2   = (const float*)d_in[13];

    float* out = (float*)d_out;
    // out layout: [0) outputs(h2) 32768 | 32768) h1 | 65536) c1 | 98304) h2 | 131072) c2
    float* ws = (float*)d_ws;
    float* partials = ws;                                  // 128*8*260 floats

    attn_partial<<<dim3(CHUNKS, BN), 256, 0, stream>>>(enc, hidden1, partials);
    lstm1_fused<<<dim3(32, 8), 256, 0, stream>>>(partials, hidden1, w_ih1, w_hh1,
                                                 b_ih1, b_hh1, cell1,
                                                 out + 32768, out + 65536);
    lstm2_kernel<<<dim3(64, 4), 256, 0, stream>>>(embed, out + 32768, hidden2,
                                                  w_ih2, w_hh2, b_ih2, b_hh2, cell2,
                                                  out, out + 98304, out + 131072);
}